// Round 2
// baseline (621.513 us; speedup 1.0000x reference)
//
#include <hip/hip_runtime.h>
#include <hip/hip_bf16.h>

// GCN layer: out = ReLU( D^-1/2 (A+I) D^-1/2 X W + b ), N=8192, IN=OUT=256.
// ALL inputs/outputs are fp32 (per reference dtypes). bf16 used internally for MFMA.
// Decomposition: s = (rowsum(adj)+1)^-1/2 ; Z = X@W ;
//   out[i,n] = relu( s_i * sum_j adj[i,j]*s_j*Z[j,n] + s_i^2*Z[i,n] + b[n] )

typedef __attribute__((ext_vector_type(8))) short short8;
typedef __attribute__((ext_vector_type(4))) short short4v;
typedef __attribute__((ext_vector_type(4))) float floatx4;

#define GLDS16(g, l) __builtin_amdgcn_global_load_lds(\
    (const __attribute__((address_space(1))) void*)(g), \
    (__attribute__((address_space(3))) void*)(l), 16, 0, 0)

// fp32 -> bf16 round-to-nearest-even
__device__ __forceinline__ unsigned short f2b(float f) {
  unsigned int x = __builtin_bit_cast(unsigned int, f);
  unsigned int r = (x + 0x7fffu + ((x >> 16) & 1u)) >> 16;
  return (unsigned short)r;
}

// ---- kernel 1: degree -> s ; WT = bf16(W^T) ; Xb = bf16(X) -----------------
__global__ __launch_bounds__(256) void k_prep(
    const float* __restrict__ adj, const float* __restrict__ W,
    const float* __restrict__ X, float* __restrict__ s,
    unsigned short* __restrict__ WT, unsigned short* __restrict__ Xb) {
  __shared__ float part[4];
  const int b = blockIdx.x, t = threadIdx.x;
  if (b < 8192) {
    const float4* row = (const float4*)(adj + (size_t)b * 8192);
    float sum = 0.f;
#pragma unroll
    for (int q = 0; q < 8; ++q) {
      float4 v = row[t + q * 256];
      sum += v.x + v.y + v.z + v.w;
    }
#pragma unroll
    for (int o = 32; o > 0; o >>= 1) sum += __shfl_down(sum, o, 64);
    if ((t & 63) == 0) part[t >> 6] = sum;
    __syncthreads();
    if (t == 0) s[b] = rsqrtf(part[0] + part[1] + part[2] + part[3] + 1.0f);
  } else if (b < 8256) {
    const int wb = b - 8192;
#pragma unroll
    for (int q = 0; q < 4; ++q) {
      int i = wb * 1024 + q * 256 + t;            // flat WT index, coalesced write
      WT[i] = f2b(W[(i & 255) * 256 + (i >> 8)]); // WT[n][k] = W[k][n]
    }
  } else {
    const int xb = b - 8256;
#pragma unroll
    for (int q = 0; q < 8; ++q) {
      int i = xb * 2048 + q * 256 + t;
      Xb[i] = f2b(X[i]);
    }
  }
}

// ---- kernel 2: Z = X@W ; Zd = s^2 Z + b (fp32) ; ZsT[n][k] = bf16(s_k Z[k][n])
__global__ __launch_bounds__(256) void k_xw(
    const unsigned short* __restrict__ Xb, const unsigned short* __restrict__ WT,
    const float* __restrict__ bias, const float* __restrict__ s,
    float* __restrict__ Zd, unsigned short* __restrict__ ZsT) {
  // 16B-unit layout: slot = kc*64 + m  (kc = k/8), conflict-free ds_read_b128
  __shared__ __align__(16) unsigned short ldsX[64 * 256];
  __shared__ __align__(16) unsigned short ldsW[64 * 256];
  const int t = threadIdx.x, l = t & 63, w = t >> 6;
  const int quad = l >> 4, nl = l & 15;
  const int m0 = blockIdx.x * 64, n0 = blockIdx.y * 64;
#pragma unroll
  for (int r = 0; r < 8; ++r) {
    int sl = r * 256 + t;
    int kc = sl >> 6, mm = sl & 63;
    GLDS16(Xb + (m0 + mm) * 256 + kc * 8, (char*)ldsX + sl * 16);
    GLDS16(WT + (n0 + mm) * 256 + kc * 8, (char*)ldsW + sl * 16);
  }
  __syncthreads();
  const int wm = w & 1, wn = w >> 1;   // 2x2 wave grid, 32x32 per wave
  floatx4 acc[2][2] = {};
#pragma unroll
  for (int kk = 0; kk < 8; ++kk) {
    int kc = kk * 4 + quad;
    short8 af[2], bf[2];
#pragma unroll
    for (int i = 0; i < 2; ++i) {
      af[i] = *(const short8*)&ldsX[(kc * 64 + wm * 32 + i * 16 + nl) * 8];
      bf[i] = *(const short8*)&ldsW[(kc * 64 + wn * 32 + i * 16 + nl) * 8];
    }
#pragma unroll
    for (int mi = 0; mi < 2; ++mi)
#pragma unroll
      for (int ni = 0; ni < 2; ++ni)
        acc[mi][ni] = __builtin_amdgcn_mfma_f32_16x16x32_bf16(af[mi], bf[ni], acc[mi][ni], 0, 0, 0);
  }
#pragma unroll
  for (int mi = 0; mi < 2; ++mi)
#pragma unroll
    for (int ni = 0; ni < 2; ++ni)
#pragma unroll
      for (int r = 0; r < 4; ++r) {
        int row = m0 + wm * 32 + mi * 16 + quad * 4 + r;   // C layout: row=quad*4+r
        int col = n0 + wn * 32 + ni * 16 + nl;             //           col=lane&15
        float v = acc[mi][ni][r];
        float sr = s[row];
        Zd[row * 256 + col] = sr * sr * v + bias[col];
        ZsT[col * 8192 + row] = f2b(sr * v);
      }
}

// ---- kernel 3: out = relu(s_i * (adj @ Zs) + Zd), fp32 adj -----------------
// BM=32, BN=256 (adj read exactly once), BK=64, 8 waves of 32x32.
// A-tile: fp32 global -> VGPR -> cvt bf16 -> ds_write (544B/kc-group padded layout).
// B-tile: bf16 ZsT via global_load_lds width=16 (layout slot = kc*256 + n).
__global__ __launch_bounds__(512) void k_main(
    const float* __restrict__ adj, const unsigned short* __restrict__ ZsT,
    const float* __restrict__ s, const float* __restrict__ Zd,
    float* __restrict__ out) {
  __shared__ __align__(16) char ldsA[8 * 544];              // 4.25 KB (pad: 544B stride)
  __shared__ __align__(16) unsigned short ldsB[64 * 256];   // 32 KB
  const int t = threadIdx.x, l = t & 63, w = t >> 6;
  const int quad = l >> 4, nl = l & 15;
  const int m0 = blockIdx.x * 32;
  const int aM = t >> 4, aC = t & 15;           // row 0..31, 4-float chunk 0..15
  const float* aSrc = adj + (size_t)(m0 + aM) * 8192 + aC * 4;
  char* aDst = ldsA + (aC >> 1) * 544 + aM * 16 + (aC & 1) * 8;
  floatx4 acc[2][2] = {};
  for (int kt = 0; kt < 128; ++kt) {
    const int k0 = kt * 64;
    __syncthreads();                       // previous tile's compute done
#pragma unroll
    for (int r = 0; r < 4; ++r) {          // B: async DMA, issue first
      int sl = r * 512 + t;
      GLDS16(ZsT + (sl & 255) * 8192 + k0 + (sl >> 8) * 8, (char*)ldsB + sl * 16);
    }
    float4 av = *(const float4*)(aSrc + k0);
    short4v ab = { (short)f2b(av.x), (short)f2b(av.y), (short)f2b(av.z), (short)f2b(av.w) };
    *(short4v*)aDst = ab;
    __syncthreads();                       // all staging drained
#pragma unroll
    for (int kk = 0; kk < 2; ++kk) {
      int kc = kk * 4 + quad;
      short8 af[2], bf[2];
      af[0] = *(const short8*)(ldsA + kc * 544 + nl * 16);
      af[1] = *(const short8*)(ldsA + kc * 544 + (16 + nl) * 16);
      bf[0] = *(const short8*)&ldsB[(kc * 256 + w * 32 + nl) * 8];
      bf[1] = *(const short8*)&ldsB[(kc * 256 + w * 32 + 16 + nl) * 8];
      acc[0][0] = __builtin_amdgcn_mfma_f32_16x16x32_bf16(af[0], bf[0], acc[0][0], 0, 0, 0);
      acc[0][1] = __builtin_amdgcn_mfma_f32_16x16x32_bf16(af[0], bf[1], acc[0][1], 0, 0, 0);
      acc[1][0] = __builtin_amdgcn_mfma_f32_16x16x32_bf16(af[1], bf[0], acc[1][0], 0, 0, 0);
      acc[1][1] = __builtin_amdgcn_mfma_f32_16x16x32_bf16(af[1], bf[1], acc[1][1], 0, 0, 0);
    }
  }
#pragma unroll
  for (int mi = 0; mi < 2; ++mi)
#pragma unroll
    for (int ni = 0; ni < 2; ++ni)
#pragma unroll
      for (int r = 0; r < 4; ++r) {
        int row = m0 + mi * 16 + quad * 4 + r;
        int col = w * 32 + ni * 16 + nl;
        float v = s[row] * acc[mi][ni][r] + Zd[row * 256 + col];
        out[row * 256 + col] = v > 0.f ? v : 0.f;
      }
}

extern "C" void kernel_launch(void* const* d_in, const int* in_sizes, int n_in,
                              void* d_out, int out_size, void* d_ws, size_t ws_size,
                              hipStream_t stream) {
  const float* X    = (const float*)d_in[0];   // [8192][256] fp32
  const float* adj  = (const float*)d_in[1];   // [8192][8192] fp32
  const float* W    = (const float*)d_in[2];   // [256][256] fp32 ([in][out])
  const float* bias = (const float*)d_in[3];   // [256] fp32
  float* out = (float*)d_out;                  // [8192][256] fp32

  char* ws = (char*)d_ws;
  float* s            = (float*)(ws);                     // 32 KB
  unsigned short* WT  = (unsigned short*)(ws + 32768);    // 128 KB bf16 W^T
  unsigned short* Xb  = (unsigned short*)(ws + 262144);   // 4 MB bf16 X
  float* Zd           = (float*)(ws + (8 << 20));         // 8 MB fp32
  unsigned short* ZsT = (unsigned short*)(ws + (16 << 20)); // 4 MB bf16  (total 20 MB)

  hipLaunchKernelGGL(k_prep, dim3(9280), dim3(256), 0, stream, adj, W, X, s, WT, Xb);
  hipLaunchKernelGGL(k_xw, dim3(128, 4), dim3(256), 0, stream, Xb, WT, bias, s, Zd, ZsT);
  hipLaunchKernelGGL(k_main, dim3(256), dim3(512), 0, stream, adj, ZsT, s, Zd, out);
}

// Round 3
// 528.567 us; speedup vs baseline: 1.1758x; 1.1758x over previous
//
#include <hip/hip_runtime.h>
#include <hip/hip_bf16.h>

// GCN layer: out = ReLU( D^-1/2 (A+I) D^-1/2 X W + b ), N=8192, IN=OUT=256.
// fp32 I/O; bf16 internally for MFMA.
//   s = (rowsum(adj)+1)^-1/2 ; Z = X@W ;
//   out[i,n] = relu( s_i * sum_j adj[i,j]*s_j*Z[j,n] + s_i^2*Z[i,n] + b[n] )
// Zsb is Zs^T pre-swizzled to the k_main LDS image:
//   short idx = kt*16384 + kc*2048 + n*8 + k7   (k = kt*64 + kc*8 + k7)

typedef __attribute__((ext_vector_type(8))) short short8;
typedef __attribute__((ext_vector_type(4))) short short4v;
typedef __attribute__((ext_vector_type(4))) float floatx4;

#define GLDS16(g, l) __builtin_amdgcn_global_load_lds(\
    (const __attribute__((address_space(1))) void*)(g), \
    (__attribute__((address_space(3))) void*)(l), 16, 0, 0)

// fp32 -> bf16 round-to-nearest-even
__device__ __forceinline__ unsigned short f2b(float f) {
  unsigned int x = __builtin_bit_cast(unsigned int, f);
  unsigned int r = (x + 0x7fffu + ((x >> 16) & 1u)) >> 16;
  return (unsigned short)r;
}

// ---- kernel 1: degree -> s ; WT = bf16(W^T) ; Xb = bf16(X) -----------------
__global__ __launch_bounds__(256) void k_prep(
    const float* __restrict__ adj, const float* __restrict__ W,
    const float* __restrict__ X, float* __restrict__ s,
    unsigned short* __restrict__ WT, unsigned short* __restrict__ Xb) {
  __shared__ float part[4];
  const int b = blockIdx.x, t = threadIdx.x;
  if (b < 8192) {
    const float4* row = (const float4*)(adj + (size_t)b * 8192);
    float sum = 0.f;
#pragma unroll
    for (int q = 0; q < 8; ++q) {
      float4 v = row[t + q * 256];
      sum += v.x + v.y + v.z + v.w;
    }
#pragma unroll
    for (int o = 32; o > 0; o >>= 1) sum += __shfl_down(sum, o, 64);
    if ((t & 63) == 0) part[t >> 6] = sum;
    __syncthreads();
    if (t == 0) s[b] = rsqrtf(part[0] + part[1] + part[2] + part[3] + 1.0f);
  } else if (b < 8256) {
    const int wb = b - 8192;
#pragma unroll
    for (int q = 0; q < 4; ++q) {
      int i = wb * 1024 + q * 256 + t;            // flat WT index, coalesced write
      WT[i] = f2b(W[(i & 255) * 256 + (i >> 8)]); // WT[n][k] = W[k][n]
    }
  } else {
    const int xb = b - 8256;
#pragma unroll
    for (int q = 0; q < 8; ++q) {
      int i = xb * 2048 + q * 256 + t;
      Xb[i] = f2b(X[i]);
    }
  }
}

// ---- kernel 2: Z = X@W ; Zd = s^2 Z + b (fp32) ; Zsb = swizzled bf16 s_k Z --
__global__ __launch_bounds__(256) void k_xw(
    const unsigned short* __restrict__ Xb, const unsigned short* __restrict__ WT,
    const float* __restrict__ bias, const float* __restrict__ s,
    float* __restrict__ Zd, unsigned short* __restrict__ Zsb) {
  // 16B-unit layout: slot = kc*64 + m  (kc = k/8), conflict-free ds_read_b128
  __shared__ __align__(16) unsigned short ldsX[64 * 256];
  __shared__ __align__(16) unsigned short ldsW[64 * 256];
  __shared__ __align__(16) unsigned short ldsT[64 * 72];  // [nn][kk], stride 72 shorts
  const int t = threadIdx.x, l = t & 63, w = t >> 6;
  const int quad = l >> 4, nl = l & 15;
  const int m0 = blockIdx.x * 64, n0 = blockIdx.y * 64;
#pragma unroll
  for (int r = 0; r < 8; ++r) {
    int sl = r * 256 + t;
    int kc = sl >> 6, mm = sl & 63;
    GLDS16(Xb + (m0 + mm) * 256 + kc * 8, (char*)ldsX + sl * 16);
    GLDS16(WT + (n0 + mm) * 256 + kc * 8, (char*)ldsW + sl * 16);
  }
  __syncthreads();
  const int wm = w & 1, wn = w >> 1;   // 2x2 wave grid, 32x32 per wave
  floatx4 acc[2][2] = {};
#pragma unroll
  for (int kk = 0; kk < 8; ++kk) {
    int kc = kk * 4 + quad;
    short8 af[2], bf[2];
#pragma unroll
    for (int i = 0; i < 2; ++i) {
      af[i] = *(const short8*)&ldsX[(kc * 64 + wm * 32 + i * 16 + nl) * 8];
      bf[i] = *(const short8*)&ldsW[(kc * 64 + wn * 32 + i * 16 + nl) * 8];
    }
#pragma unroll
    for (int mi = 0; mi < 2; ++mi)
#pragma unroll
      for (int ni = 0; ni < 2; ++ni)
        acc[mi][ni] = __builtin_amdgcn_mfma_f32_16x16x32_bf16(af[mi], bf[ni], acc[mi][ni], 0, 0, 0);
  }
#pragma unroll
  for (int mi = 0; mi < 2; ++mi)
#pragma unroll
    for (int ni = 0; ni < 2; ++ni)
#pragma unroll
      for (int r = 0; r < 4; ++r) {
        int row = m0 + wm * 32 + mi * 16 + quad * 4 + r;   // C layout: row=quad*4+r
        int col = n0 + wn * 32 + ni * 16 + nl;             //           col=lane&15
        float v = acc[mi][ni][r];
        float sr = s[row];
        Zd[row * 256 + col] = sr * sr * v + bias[col];
        ldsT[(col - n0) * 72 + (row - m0)] = f2b(sr * v);  // transpose via LDS
      }
  __syncthreads();
  // write 512 16B chunks: c -> kc = c>>6, nn = c&63; lanes contiguous in nn -> 1KB stores
#pragma unroll
  for (int h = 0; h < 2; ++h) {
    int c = h * 256 + t;
    int kc = c >> 6, nn = c & 63;
    short8 val = *(const short8*)&ldsT[nn * 72 + kc * 8];
    *(short8*)(Zsb + (size_t)blockIdx.x * 16384 + kc * 2048 + (n0 + nn) * 8) = val;
  }
}

// ---- kernel 3: out = relu(s_i * (adj @ Zs) + Zd) ---------------------------
// BM=32, BN=256 (adj read exactly once), BK=64, 8 waves of 32x32, double-buffered.
__global__ __launch_bounds__(512) void k_main(
    const float* __restrict__ adj, const unsigned short* __restrict__ Zsb,
    const float* __restrict__ s, const float* __restrict__ Zd,
    float* __restrict__ out) {
  __shared__ __align__(16) char ldsA[2][8 * 544];            // 2 x 4.25 KB (544B stride pad)
  __shared__ __align__(16) unsigned short ldsB[2][64 * 256]; // 2 x 32 KB
  const int t = threadIdx.x, l = t & 63, w = t >> 6;
  const int quad = l >> 4, nl = l & 15;
  const int m0 = blockIdx.x * 32;
  const int aM = t >> 4, aC = t & 15;           // A stage: row 0..31, 4-float chunk 0..15
  const float* aSrc = adj + (size_t)(m0 + aM) * 8192 + aC * 4;
  const int aOff = (aC >> 1) * 544 + aM * 16 + (aC & 1) * 8;
  floatx4 acc[2][2] = {};

  // ---- prologue: tile 0 (A load first so its wait is vmcnt(4), not a drain)
  float4 av = *(const float4*)(aSrc);
#pragma unroll
  for (int r = 0; r < 4; ++r) {
    int sl = r * 512 + t;
    GLDS16(Zsb + (size_t)sl * 8, (char*)ldsB[0] + sl * 16);
  }
  {
    short4v ab = {(short)f2b(av.x), (short)f2b(av.y), (short)f2b(av.z), (short)f2b(av.w)};
    *(short4v*)(ldsA[0] + aOff) = ab;
  }
  __syncthreads();

  for (int kt = 0; kt < 128; ++kt) {
    const int cur = kt & 1, nxt = cur ^ 1;
    const int ktn = (kt < 127) ? kt + 1 : 127;   // last prefetch redundant, in-bounds
    // prefetch tile kt+1: A (VGPR) first, then B (GLDS DMA) — in flight during compute
    av = *(const float4*)(aSrc + (size_t)ktn * 64);
#pragma unroll
    for (int r = 0; r < 4; ++r) {
      int sl = r * 512 + t;
      GLDS16(Zsb + (size_t)(ktn * 2048 + sl) * 8, (char*)ldsB[nxt] + sl * 16);
    }
    // compute tile kt
#pragma unroll
    for (int kk = 0; kk < 2; ++kk) {
      int kc = kk * 4 + quad;
      short8 af[2], bf[2];
      af[0] = *(const short8*)(ldsA[cur] + kc * 544 + nl * 16);
      af[1] = *(const short8*)(ldsA[cur] + kc * 544 + (16 + nl) * 16);
      bf[0] = *(const short8*)&ldsB[cur][(kc * 256 + w * 32 + nl) * 8];
      bf[1] = *(const short8*)&ldsB[cur][(kc * 256 + w * 32 + 16 + nl) * 8];
      acc[0][0] = __builtin_amdgcn_mfma_f32_16x16x32_bf16(af[0], bf[0], acc[0][0], 0, 0, 0);
      acc[0][1] = __builtin_amdgcn_mfma_f32_16x16x32_bf16(af[0], bf[1], acc[0][1], 0, 0, 0);
      acc[1][0] = __builtin_amdgcn_mfma_f32_16x16x32_bf16(af[1], bf[0], acc[1][0], 0, 0, 0);
      acc[1][1] = __builtin_amdgcn_mfma_f32_16x16x32_bf16(af[1], bf[1], acc[1][1], 0, 0, 0);
    }
    // stage A tile kt+1 into the other buffer (waits only vmcnt(4) for av)
    {
      short4v ab = {(short)f2b(av.x), (short)f2b(av.y), (short)f2b(av.z), (short)f2b(av.w)};
      *(short4v*)(ldsA[nxt] + aOff) = ab;
    }
    __syncthreads();   // drains tile kt+1's GLDS (in flight during compute above)
  }

#pragma unroll
  for (int mi = 0; mi < 2; ++mi)
#pragma unroll
    for (int ni = 0; ni < 2; ++ni)
#pragma unroll
      for (int r = 0; r < 4; ++r) {
        int row = m0 + mi * 16 + quad * 4 + r;
        int col = w * 32 + ni * 16 + nl;
        float v = s[row] * acc[mi][ni][r] + Zd[row * 256 + col];
        out[row * 256 + col] = v > 0.f ? v : 0.f;
      }
}

extern "C" void kernel_launch(void* const* d_in, const int* in_sizes, int n_in,
                              void* d_out, int out_size, void* d_ws, size_t ws_size,
                              hipStream_t stream) {
  const float* X    = (const float*)d_in[0];   // [8192][256] fp32
  const float* adj  = (const float*)d_in[1];   // [8192][8192] fp32
  const float* W    = (const float*)d_in[2];   // [256][256] fp32 ([in][out])
  const float* bias = (const float*)d_in[3];   // [256] fp32
  float* out = (float*)d_out;                  // [8192][256] fp32

  char* ws = (char*)d_ws;
  float* s            = (float*)(ws);                       // 32 KB
  unsigned short* WT  = (unsigned short*)(ws + 32768);      // 128 KB bf16 W^T
  unsigned short* Xb  = (unsigned short*)(ws + 262144);     // 4 MB bf16 X
  float* Zd           = (float*)(ws + (8 << 20));           // 8 MB fp32
  unsigned short* Zsb = (unsigned short*)(ws + (16 << 20)); // 4 MB bf16 swizzled

  hipLaunchKernelGGL(k_prep, dim3(9280), dim3(256), 0, stream, adj, W, X, s, WT, Xb);
  hipLaunchKernelGGL(k_xw, dim3(128, 4), dim3(256), 0, stream, Xb, WT, bias, s, Zd, Zsb);
  hipLaunchKernelGGL(k_main, dim3(256), dim3(512), 0, stream, adj, Zsb, s, Zd, out);
}